// Round 5
// baseline (173.863 us; speedup 1.0000x reference)
//
#include <hip/hip_runtime.h>

// S = 1024*1024, ranks [1,3,3,3,3,1].
#define SDIM (1024 * 1024)
#define TILE_S 1024               // s-values per block (3072 floats = 12 KB of t-plane)
#define CHUNKS (SDIM / TILE_S)    // 1024 tiles per plane
#define NPLANE 10                 // TT0 (1 plane) + TT1..TT3 (3 planes each)

// K1: grid (CHUNKS, NPLANE). partial[plane][tile][q] = sum_{s in tile} z[s]*plane[3s+q].
// All global loads are wave-contiguous (lane stride 16 B, 8 cache lines per
// instruction) — R2..R4 showed the 48-B-stride pattern pins the kernel at
// ~4 TB/s even when fully cache-resident (3x TA transactions per byte).
// Lane-phase rotation: lane holds floats u..u+3 of the plane (u = w*768 +
// j*256 + 4*lane); float u+m has s=(u+m)/3, q=(u+m)%3. Accumulate into slot
// b[(j+m)%3] (slot t of lane means q=(phi+t)%3, phi=lane%3), pair with
// z[s0]/z[s0+1] from an LDS stage, un-rotate once at the end.
__global__ __launch_bounds__(256) void ftt_k1(
    const float* __restrict__ z,
    const float* __restrict__ t0,
    const float* __restrict__ t1,
    const float* __restrict__ t2,
    const float* __restrict__ t3,
    float* __restrict__ partials)   // [NPLANE][CHUNKS][4]
{
    const int plane = blockIdx.y;
    const int tile  = blockIdx.x;
    const int tid   = threadIdx.x;
    const int w     = tid >> 6;     // wave 0..3
    const int lane  = tid & 63;

    const float* base;
    if (plane == 0) {
        base = t0;
    } else {
        const int pk = plane - 1;
        const int k  = pk / 3;                       // wave-uniform
        const float* tk = (k == 0) ? t1 : (k == 1) ? t2 : t3;
        base = tk + (pk % 3) * (3 * SDIM);
    }

    // Stage this tile's z (1024 floats) to LDS: one coalesced float4/thread.
    __shared__ float zt[TILE_S];
    const float4 z4 = reinterpret_cast<const float4*>(z)[tile * 256 + tid];

    // Three wave-contiguous float4 loads of the plane span (issue up front).
    const float4* b4 = reinterpret_cast<const float4*>(base)
                     + (size_t)tile * 768 + w * 192 + lane;
    const float4 v0 = b4[0];
    const float4 v1 = b4[64];
    const float4 v2 = b4[128];

    reinterpret_cast<float4*>(zt)[tid] = z4;
    __syncthreads();

    float b0 = 0.f, b1 = 0.f, b2 = 0.f;
    const int phi = lane % 3;

    {   // j = 0: slots m0..m3 -> b0,b1,b2,b0 ; p = phi
        const int s0 = w * 256 + (4 * lane) / 3;
        const float za = zt[s0], zb = zt[s0 + 1];
        const int p = phi;
        const float zm1 = (p < 2) ? za : zb;
        const float zm2 = (p == 0) ? za : zb;
        b0 += v0.x * za;  b1 += v0.y * zm1;  b2 += v0.z * zm2;  b0 += v0.w * zb;
    }
    {   // j = 1: slots -> b1,b2,b0,b1 ; p = (phi+1)%3
        const int s0 = w * 256 + (256 + 4 * lane) / 3;
        const float za = zt[s0], zb = zt[s0 + 1];
        int p = phi + 1; if (p >= 3) p -= 3;
        const float zm1 = (p < 2) ? za : zb;
        const float zm2 = (p == 0) ? za : zb;
        b1 += v1.x * za;  b2 += v1.y * zm1;  b0 += v1.z * zm2;  b1 += v1.w * zb;
    }
    {   // j = 2: slots -> b2,b0,b1,b2 ; p = (phi+2)%3
        const int s0 = w * 256 + (512 + 4 * lane) / 3;
        const float za = zt[s0], zb = zt[s0 + 1];
        int p = phi + 2; if (p >= 3) p -= 3;
        const float zm1 = (p < 2) ? za : zb;
        const float zm2 = (p == 0) ? za : zb;
        b2 += v2.x * za;  b0 += v2.y * zm1;  b1 += v2.z * zm2;  b2 += v2.w * zb;
    }

    // Un-rotate: slot t of this lane holds q = (phi + t) % 3.
    float a0 = (phi == 0) ? b0 : (phi == 1) ? b2 : b1;
    float a1 = (phi == 0) ? b1 : (phi == 1) ? b0 : b2;
    float a2 = (phi == 0) ? b2 : (phi == 1) ? b1 : b0;

    // wave (64) shuffle reduction
    #pragma unroll
    for (int off = 32; off > 0; off >>= 1) {
        a0 += __shfl_down(a0, off, 64);
        a1 += __shfl_down(a1, off, 64);
        a2 += __shfl_down(a2, off, 64);
    }

    __shared__ float red[4][3];
    if (lane == 0) { red[w][0] = a0; red[w][1] = a1; red[w][2] = a2; }
    __syncthreads();
    if (tid < 3) {
        const float s = red[0][tid] + red[1][tid] + red[2][tid] + red[3][tid];
        partials[(plane * CHUNKS + tile) * 4 + tid] = s;
    }
}

// K2: reduce [NPLANE][CHUNKS] partial triples -> 30 sums -> f = V0@V1@V2@V3 (3 floats)
__global__ __launch_bounds__(256) void ftt_k2(
    const float* __restrict__ partials,
    float* __restrict__ fvec)
{
    __shared__ float red[NPLANE * 3][8];
    const int job = threadIdx.x >> 3;   // 0..31 (30 used): job = plane*3 + c
    const int sub = threadIdx.x & 7;    // 8 threads per job, CHUNKS/8 each
    if (job < NPLANE * 3) {
        const int plane = job / 3, c = job % 3;
        float s = 0.0f;
        const int b0 = sub * (CHUNKS / 8);
        #pragma unroll 4
        for (int b = b0; b < b0 + (CHUNKS / 8); ++b)
            s += partials[(plane * CHUNKS + b) * 4 + c];
        red[job][sub] = s;
    }
    __syncthreads();

    if (threadIdx.x == 0) {
        float sum[NPLANE * 3];
        #pragma unroll
        for (int i = 0; i < NPLANE * 3; ++i) {
            float t = 0.0f;
            #pragma unroll
            for (int g = 0; g < 8; ++g) t += red[i][g];
            sum[i] = t;
        }
        float f0 = sum[0], f1 = sum[1], f2 = sum[2];
        #pragma unroll
        for (int k = 0; k < 3; ++k) {
            const float* V = &sum[3 + k * 9];   // V[r*3+q]
            const float n0 = f0 * V[0] + f1 * V[3] + f2 * V[6];
            const float n1 = f0 * V[1] + f1 * V[4] + f2 * V[7];
            const float n2 = f0 * V[2] + f1 * V[5] + f2 * V[8];
            f0 = n0; f1 = n1; f2 = n2;
        }
        fvec[0] = f0; fvec[1] = f1; fvec[2] = f2;
    }
}

// K3: out[s] = f0*TT4[0,s] + f1*TT4[1,s] + f2*TT4[2,s]   (TT4 is (3,S,1))
__global__ __launch_bounds__(256) void ftt_k3(
    const float* __restrict__ t4,
    const float* __restrict__ fvec,
    float* __restrict__ out)
{
    const int i0 = (blockIdx.x * blockDim.x + threadIdx.x) * 2; // float4 index
    const float f0 = fvec[0], f1 = fvec[1], f2 = fvec[2];
    const float4* pa = reinterpret_cast<const float4*>(t4);
    const float4* pb = reinterpret_cast<const float4*>(t4 + SDIM);
    const float4* pc = reinterpret_cast<const float4*>(t4 + 2 * SDIM);
    const float4 aA = pa[i0], bA = pb[i0], cA = pc[i0];
    const float4 aB = pa[i0 + 1], bB = pb[i0 + 1], cB = pc[i0 + 1];
    float4 oA, oB;
    oA.x = f0 * aA.x + f1 * bA.x + f2 * cA.x;
    oA.y = f0 * aA.y + f1 * bA.y + f2 * cA.y;
    oA.z = f0 * aA.z + f1 * bA.z + f2 * cA.z;
    oA.w = f0 * aA.w + f1 * bA.w + f2 * cA.w;
    oB.x = f0 * aB.x + f1 * bB.x + f2 * cB.x;
    oB.y = f0 * aB.y + f1 * bB.y + f2 * cB.y;
    oB.z = f0 * aB.z + f1 * bB.z + f2 * cB.z;
    oB.w = f0 * aB.w + f1 * bB.w + f2 * cB.w;
    reinterpret_cast<float4*>(out)[i0] = oA;
    reinterpret_cast<float4*>(out)[i0 + 1] = oB;
}

extern "C" void kernel_launch(void* const* d_in, const int* in_sizes, int n_in,
                              void* d_out, int out_size, void* d_ws, size_t ws_size,
                              hipStream_t stream)
{
    const float* z  = (const float*)d_in[0];
    const float* t0 = (const float*)d_in[1];
    const float* t1 = (const float*)d_in[2];
    const float* t2 = (const float*)d_in[3];
    const float* t3 = (const float*)d_in[4];
    const float* t4 = (const float*)d_in[5];
    float* out = (float*)d_out;

    float* partials = (float*)d_ws;                      // NPLANE*CHUNKS*4 floats = 160 KB
    float* fvec     = partials + NPLANE * CHUNKS * 4;    // 3 floats

    ftt_k1<<<dim3(CHUNKS, NPLANE), 256, 0, stream>>>(z, t0, t1, t2, t3, partials);
    ftt_k2<<<1, 256, 0, stream>>>(partials, fvec);
    ftt_k3<<<SDIM / 4 / 256 / 2, 256, 0, stream>>>(t4, fvec, out);
}